// Round 5
// baseline (220.637 us; speedup 1.0000x reference)
//
#include <hip/hip_runtime.h>
#include <cstdint>

// DetNet NMS, round 23. r22 post-mortem: serial kept-row ORs cost +20us over
// r19 => kept ~ 150-350; r19's 45us tail = per-chunk helper pipeline latency.
// Every full-mask variant pays kept-row mask propagation on/near the critical
// path. r23: DROP the V x V mask entirely.
//   builders (64 blocks): diagonal-only in-chunk 128x128 masks -> compact
//       mdiag[8192][2] u64 (128 KB), ~16K IoUs/chunk, all chunks ready ~2us;
//       publish doneD[c]=MAGIC (release, after threadfence; poison-safe --
//       MAGIC pattern validated vs poison in r20).
//   consumer (block 0): per chunk T: phase A (wave 0) = ballot dead flags,
//       serial in-chunk resolve via mdiag band (identical scan as r18-r22),
//       append kept to LDS kept-list (boxes+areas+rows, spill to global past
//       MAXK); phase C (all 512) = IoU of chunk T+1's 128 boxes vs kept list
//       (q=t>>7 partitions kept range; LDS broadcast reads), set dead flags.
//       Kept list complete through T when C runs => no cascade, no helpers,
//       no handshake. Out rows written in one pass at the end.
// Cross-chunk suppression moves from 8M precomputed IoUs + mask traffic to
// ~V*kept/2 ~ 0.5M on-the-fly IoUs on the consumer block.
// All decision-critical FP math __f*_rn in exact ref op order (suppressor
// area first in union add, __fdiv_rn kept). absmax 0.0 r1-4,6-9,11-15,17-22.

#define M_TOT 8192
#define NMS_T 0.3f
#define MAGIC 0x5F3C9B71u
#define MAXK  4096

// ws layout (bytes)
#define WS_BOX   65536      // float4[8192] boxes_srt
#define WS_D     196608     // float[40960] d_srt
#define WS_VCNT  360448     // u32
#define WS_DONED 360512     // u32[64] per-chunk diag-built flags (MAGIC)
#define WS_MDIAG 393216     // ulonglong2[8192] in-chunk diag mask (131072 B)
#define WS_KBG   524288     // float4[8192] kept-box spill (131072 B)
#define WS_KRG   655360     // u32[8192] kept-row spill (32768 B)

typedef unsigned long long u64t;

__device__ __forceinline__ uint32_t desc_key(float sv) {
    uint32_t u = __float_as_uint(sv);
    uint32_t m = (u & 0x80000000u) ? ~u : (u | 0x80000000u);
    return ~m;
}
__device__ __forceinline__ u64t rdl64(u64t v, int sl) {
    unsigned lo = (unsigned)__builtin_amdgcn_readlane((int)(unsigned)v, sl);
    unsigned hi = (unsigned)__builtin_amdgcn_readlane((int)(unsigned)(v >> 32), sl);
    return ((u64t)hi << 32) | lo;
}

__device__ __forceinline__ void scatter_one(
    int i, int rank, u64t key,
    const float* __restrict__ det, const float* __restrict__ offsets,
    const float* __restrict__ scales,
    float4* __restrict__ boxes_srt, float* __restrict__ d_srt)
{
    uint32_t dkey = (uint32_t)(key >> 16);
    if (dkey >= 0x7FFFFFFFu) return;     // score <= 0: row stays zero
    int g = i >> 10;
    float d0 = __fadd_rn(offsets[g*5+0], __fmul_rn(det[i*5+0], scales[g*5+0]));
    float d1 = __fadd_rn(offsets[g*5+1], __fmul_rn(det[i*5+1], scales[g*5+1]));
    float d2 = __fadd_rn(offsets[g*5+2], __fmul_rn(det[i*5+2], scales[g*5+2]));
    float d3 = __fadd_rn(offsets[g*5+3], __fmul_rn(det[i*5+3], scales[g*5+3]));
    float d4 = __fadd_rn(offsets[g*5+4], __fmul_rn(det[i*5+4], scales[g*5+4]));
    d_srt[rank*5+0] = d0; d_srt[rank*5+1] = d1; d_srt[rank*5+2] = d2;
    d_srt[rank*5+3] = d3; d_srt[rank*5+4] = d4;
    float hw = __fmul_rn(d3, 0.5f), hh = __fmul_rn(d4, 0.5f);
    boxes_srt[rank] = make_float4(__fsub_rn(d1, hw), __fsub_rn(d2, hh),
                                  __fadd_rn(d1, hw), __fadd_rn(d2, hh));
}

// 128 blocks x 512 threads (r19-proven, zrow/done zeroing dropped)
__global__ __launch_bounds__(512) void k2_rank(
    const float* __restrict__ det, const float* __restrict__ offsets,
    const float* __restrict__ scales, const float* __restrict__ bounds,
    float4* __restrict__ boxes_srt, float* __restrict__ d_srt,
    unsigned int* __restrict__ vcnt, float* __restrict__ out)
{
    __shared__ u64t skey[M_TOT];
    __shared__ float soff[40], sscl[40], sbnd[32];
    __shared__ int sTop;
    int t = threadIdx.x;
    int lane = t & 63;
    if (t == 0) sTop = 0;
    if (t < 40) { soff[t] = offsets[t]; sscl[t] = scales[t]; }
    if (t < 32) { sbnd[t] = bounds[t]; }
    __syncthreads();

    #pragma unroll 4
    for (int s = 0; s < 16; ++s) {
        int u = s * 512 + t;
        int g = u >> 10;
        float raw_s = det[u * 5 + 0];
        float cx    = det[u * 5 + 1];
        float cy    = det[u * 5 + 2];
        float score = __fadd_rn(soff[g * 5 + 0], __fmul_rn(raw_s, sscl[g * 5 + 0]));
        bool valid = (cx < sbnd[g*4+1]) && (cx > sbnd[g*4+0]) &&
                     (cy < sbnd[g*4+3]) && (cy > sbnd[g*4+2]);
        float sv = valid ? score : -1.0f;
        uint32_t dk = desc_key(sv);
        bool push = dk < 0x7FFFFFFFu;
        u64t key = ((u64t)dk << 16) | (unsigned)u;
        u64t bal = __ballot(push);
        if (bal) {
            int lw = 0;
            if (lane == 0) lw = atomicAdd(&sTop, __popcll(bal));
            int wbase = __builtin_amdgcn_readfirstlane(lw);
            if (push) {
                int off = __popcll(bal & ((1ull << lane) - 1ull));
                skey[wbase + off] = key;
            }
        }
    }
    __syncthreads();
    int V = sTop;
    int Vpad = (V + 15) & ~15;
    if (t < Vpad - V) skey[V + t] = ~0ull;
    {
        int zb = blockIdx.x * 320;       // 128 blocks x 320 = 40960
        for (int z = zb + t; z < zb + 320; z += 512) out[z] = 0.0f;
    }
    __syncthreads();
    if (t == 0) *vcnt = (unsigned)V;

    int grp = t >> 3;                    // 0..63
    int jq  = t & 7;
    int i = blockIdx.x * 64 + grp;       // 128*64 = 8192
    int g = i >> 10;
    float raw_s = det[i * 5 + 0];
    float cx    = det[i * 5 + 1];
    float cy    = det[i * 5 + 2];
    float score = __fadd_rn(soff[g * 5 + 0], __fmul_rn(raw_s, sscl[g * 5 + 0]));
    bool valid = (cx < sbnd[g*4+1]) && (cx > sbnd[g*4+0]) &&
                 (cy < sbnd[g*4+3]) && (cy > sbnd[g*4+2]);
    float sv = valid ? score : -1.0f;
    uint32_t dk = desc_key(sv);
    u64t ki = ((u64t)dk << 16) | (unsigned)i;
    const ulonglong2* skey2 = (const ulonglong2*)skey;
    int c = 0;
    int nit = Vpad >> 4;
    #pragma unroll 4
    for (int it = 0; it < nit; ++it) {
        ulonglong2 kj = skey2[it * 8 + jq];
        c += (kj.x < ki) + (kj.y < ki);
    }
    c += __shfl_xor(c, 1);
    c += __shfl_xor(c, 2);
    c += __shfl_xor(c, 4);
    if (jq == 0)
        scatter_one(i, c, ki, det, offsets, scales, boxes_srt, d_srt);
}

// ---- diag-mask builders + on-the-fly NMS consumer ----
// block 0: consumer; blocks 1..64: one diag chunk each.
__global__ __launch_bounds__(512) void k34_onfly(
    const float4* __restrict__ boxes_srt,
    const float* __restrict__ d_srt,
    const unsigned int* __restrict__ vcnt,
    ulonglong2* __restrict__ mdiag,
    unsigned int* __restrict__ doneD,
    float4* __restrict__ kb_g,
    unsigned int* __restrict__ kr_g,
    float* __restrict__ out)
{
    __shared__ float4 kb[MAXK];          // kept boxes
    __shared__ float  ka[MAXK];          // kept areas
    __shared__ unsigned int kr[MAXK];    // kept sorted-row indices
    __shared__ float4 cb[128];           // current-chunk boxes
    __shared__ float  ca[128];           // current-chunk areas
    __shared__ unsigned int sf32[2][128];// per-box supp flags (4 bytes = 4 q's)
    __shared__ int s_nk;

    int V = (int)*vcnt;
    int nc = (V + 127) >> 7;
    int t = threadIdx.x;

    if (blockIdx.x != 0) {
        // ---------------- builder: chunk c diag mask ----------------
        int c = (int)blockIdx.x - 1;
        if (c >= nc) return;
        if (t < 128) {
            float4 b = boxes_srt[c * 128 + t];
            cb[t] = b;
            ca[t] = __fmul_rn(fmaxf(__fsub_rn(b.z, b.x), 0.0f),
                              fmaxf(__fsub_rn(b.w, b.y), 0.0f));
        }
        __syncthreads();
        int rl = t & 127, q = t >> 7;    // all lanes of a wave share q
        float4 bi = cb[rl];
        float  ai = ca[rl];
        unsigned bits = 0u;
        int j0 = 32 * q;
        #pragma unroll 8
        for (int b = 0; b < 32; ++b) {
            int jl = j0 + b;
            float4 bj = cb[jl];
            float  aj = ca[jl];
            float iw = fmaxf(__fsub_rn(fminf(bi.z, bj.z), fmaxf(bi.x, bj.x)), 0.0f);
            float ih = fmaxf(__fsub_rn(fminf(bi.w, bj.w), fmaxf(bi.y, bj.y)), 0.0f);
            float inter = __fmul_rn(iw, ih);
            float uni   = __fsub_rn(__fadd_rn(ai, aj), inter);
            float iou   = __fdiv_rn(inter, fmaxf(uni, 1e-9f));
            if (jl > rl && iou > NMS_T) bits |= 1u << b;
        }
        ((unsigned*)mdiag)[(c * 128 + rl) * 4 + q] = bits;
        __syncthreads();
        if (t == 0) {
            __threadfence();
            __hip_atomic_store(&doneD[c], MAGIC,
                               __ATOMIC_RELEASE, __HIP_MEMORY_SCOPE_AGENT);
        }
        return;
    }

    // ---------------- consumer ----------------
    int lane = t & 63, wv = t >> 6;
    if (t == 0) s_nk = 0;
    if (t < 128) {
        float4 b = boxes_srt[t];
        cb[t] = b;
        ca[t] = __fmul_rn(fmaxf(__fsub_rn(b.z, b.x), 0.0f),
                          fmaxf(__fsub_rn(b.w, b.y), 0.0f));
    }
    if (t < 256) sf32[t >> 7][t & 127] = 0u;
    __syncthreads();
    if (nc <= 0) return;

    ulonglong2 bl, bh;                   // diag band, wave 0 only
    if (wv == 0) {
        while (__hip_atomic_load(&doneD[0], __ATOMIC_RELAXED,
                                 __HIP_MEMORY_SCOPE_AGENT) != MAGIC)
            __builtin_amdgcn_s_sleep(2);
        (void)__hip_atomic_load(&doneD[0], __ATOMIC_ACQUIRE,
                                __HIP_MEMORY_SCOPE_AGENT);
        bl = mdiag[lane];
        bh = mdiag[64 + lane];
    }

    for (int T = 0; T < nc; ++T) {
        // ---- phase A: serial in-chunk resolve + append (wave 0) ----
        if (wv == 0) {
            ulonglong2 nbl, nbh;
            bool hn = (T + 1 < nc);
            if (hn) {                    // prefetch next diag band
                while (__hip_atomic_load(&doneD[T + 1], __ATOMIC_RELAXED,
                                         __HIP_MEMORY_SCOPE_AGENT) != MAGIC)
                    __builtin_amdgcn_s_sleep(2);
                (void)__hip_atomic_load(&doneD[T + 1], __ATOMIC_ACQUIRE,
                                        __HIP_MEMORY_SCOPE_AGENT);
                nbl = mdiag[(T + 1) * 128 + lane];
                nbh = mdiag[(T + 1) * 128 + 64 + lane];
            }
            int par = T & 1;
            unsigned flo = sf32[par][lane];
            unsigned fhi = sf32[par][64 + lane];
            u64t live_lo = ~__ballot(flo != 0u);
            u64t live_hi = ~__ballot(fhi != 0u);
            int rem = V - T * 128;
            if (rem < 128) {
                live_lo &= (rem >= 64) ? ~0ull : ((rem <= 0) ? 0ull : ((1ull << rem) - 1ull));
                int rh2 = rem - 64;
                live_hi &= (rh2 >= 64) ? ~0ull : ((rh2 <= 0) ? 0ull : ((1ull << rh2) - 1ull));
            }
            u64t km_lo = 0, km_hi = 0;
            while (live_lo) {
                int bs = (int)__builtin_ctzll(live_lo);
                km_lo |= 1ull << bs;
                u64t rml = rdl64(bl.x, bs);
                u64t rmh = rdl64(bl.y, bs);
                live_lo &= ~rml & ~(1ull << bs);
                live_hi &= ~rmh;
            }
            while (live_hi) {
                int bs = (int)__builtin_ctzll(live_hi);
                km_hi |= 1ull << bs;
                u64t rmh = rdl64(bh.y, bs);   // bh.x irrelevant: live_lo==0
                live_hi &= ~rmh & ~(1ull << bs);
            }
            // append kept (parallel across wave-0 lanes)
            int pl = __popcll(km_lo);
            int nkm = pl + __popcll(km_hi);
            int snk = s_nk;
            for (int p = 0; p < 2; ++p) {
                int idx = lane + 64 * p;
                if (idx < nkm) {
                    int rl2;
                    if (idx < pl) {
                        u64t x = km_lo;
                        for (int k = 0; k < idx; ++k) x &= x - 1;
                        rl2 = (int)__builtin_ctzll(x);
                    } else {
                        u64t x = km_hi;
                        int ii = idx - pl;
                        for (int k = 0; k < ii; ++k) x &= x - 1;
                        rl2 = 64 + (int)__builtin_ctzll(x);
                    }
                    int r = T * 128 + rl2;
                    float4 b = cb[rl2];
                    float  a = ca[rl2];
                    int o = snk + idx;
                    kb_g[o] = b;                 // unconditional spill copy
                    kr_g[o] = (unsigned)r;
                    if (o < MAXK) { kb[o] = b; ka[o] = a; kr[o] = (unsigned)r; }
                }
            }
            if (t == 0) s_nk = snk + nkm;
            if (hn) { bl = nbl; bh = nbh; }
        } else {
            // waves 1-2: zero next-parity flags (disjoint from A's reads)
            if (t >= 64 && t < 192) sf32[(T + 1) & 1][t - 64] = 0u;
        }
        __syncthreads();
        // ---- phase C: chunk T+1 vs kept list (all 512 threads) ----
        if (T + 1 < nc) {
            int rl3 = t & 127, q = t >> 7;
            int r2 = (T + 1) * 128 + rl3;
            float4 br = boxes_srt[r2];
            float  ar = __fmul_rn(fmaxf(__fsub_rn(br.z, br.x), 0.0f),
                                  fmaxf(__fsub_rn(br.w, br.y), 0.0f));
            if (q == 0) { cb[rl3] = br; ca[rl3] = ar; }
            int nk = s_nk;
            int nkq = (nk + 3) >> 2;
            int jb = q * nkq;
            int je = jb + nkq; if (je > nk) je = nk;
            bool supp = false;
            for (int j = jb; j < je; ++j) {
                float4 bj; float aj;
                if (j < MAXK) { bj = kb[j]; aj = ka[j]; }
                else {
                    bj = kb_g[j];
                    aj = __fmul_rn(fmaxf(__fsub_rn(bj.z, bj.x), 0.0f),
                                   fmaxf(__fsub_rn(bj.w, bj.y), 0.0f));
                }
                float iw = fmaxf(__fsub_rn(fminf(bj.z, br.z), fmaxf(bj.x, br.x)), 0.0f);
                float ih = fmaxf(__fsub_rn(fminf(bj.w, br.w), fmaxf(bj.y, br.y)), 0.0f);
                float inter = __fmul_rn(iw, ih);
                float uni   = __fsub_rn(__fadd_rn(aj, ar), inter);
                float iou   = __fdiv_rn(inter, fmaxf(uni, 1e-9f));
                supp = supp || (iou > NMS_T);
            }
            if (supp)
                ((volatile unsigned char*)&sf32[(T + 1) & 1][rl3])[q] = 1;
        }
        __syncthreads();
    }

    // ---- final: write kept output rows ----
    {
        int nk = s_nk;
        for (int idx = t; idx < nk; idx += 512) {
            int r = (int)((idx < MAXK) ? kr[idx] : kr_g[idx]);
            out[r * 5 + 0] = d_srt[r * 5 + 0];
            out[r * 5 + 1] = d_srt[r * 5 + 1];
            out[r * 5 + 2] = d_srt[r * 5 + 2];
            out[r * 5 + 3] = d_srt[r * 5 + 3];
            out[r * 5 + 4] = d_srt[r * 5 + 4];
        }
    }
}

extern "C" void kernel_launch(void* const* d_in, const int* in_sizes, int n_in,
                              void* d_out, int out_size, void* d_ws, size_t ws_size,
                              hipStream_t stream) {
    const float* det     = (const float*)d_in[0];
    const float* offsets = (const float*)d_in[1];
    const float* scales  = (const float*)d_in[2];
    const float* bounds  = (const float*)d_in[3];
    float* out = (float*)d_out;
    char* ws = (char*)d_ws;
    float4*       boxes = (float4*)(ws + WS_BOX);
    float*        d_srt = (float*)(ws + WS_D);
    unsigned int* vcnt  = (unsigned int*)(ws + WS_VCNT);
    unsigned int* doneD = (unsigned int*)(ws + WS_DONED);
    ulonglong2*   mdiag = (ulonglong2*)(ws + WS_MDIAG);
    float4*       kb_g  = (float4*)(ws + WS_KBG);
    unsigned int* kr_g  = (unsigned int*)(ws + WS_KRG);

    k2_rank<<<128, 512, 0, stream>>>(det, offsets, scales, bounds, boxes, d_srt,
                                     vcnt, out);
    k34_onfly<<<65, 512, 0, stream>>>(boxes, d_srt, vcnt, mdiag, doneD,
                                      kb_g, kr_g, out);
}

// Round 6
// 174.751 us; speedup vs baseline: 1.2626x; 1.2626x over previous
//
#include <hip/hip_runtime.h>
#include <cstdint>

// DetNet NMS, round 24. r23 post-mortem: phase C (all-kept vs next chunk on
// ONE block) = ~11K cyc/chunk => kept ~ 500-700, V ~ 5000+, nc ~ 40-45.
// This reconciles r19 (66 = 21 build-gate + 1.4us/chunk chain), r22 (+20us =
// kept x 175cyc), r23 (149us). Diagnosis stands: 8MB mask is 95% waste.
// r24 = r23 + WORKER OFFLOAD of old-kept suppression:
//   workers (2 blocks/chunk, 128): diag 128x128 mask (publish stat[c]+=1
//     per half), then incremental suppression of their 64 boxes vs kept as
//     consumer publishes kwmnk=(NK<<32|chunksResolved) (release/acquire via
//     kb_g/knk_g), covering kept through chunk c-3; write sfg[c] half,
//     publish stat[c]+=4. Workers wait only on consumer PAST publishes ->
//     acyclic, deadlock-free. stat[c]==10 <=> band+flags ready (one poll).
//   consumer (block 0): per chunk T: flags = worker sfg (prefetched 1 ahead)
//     | residual sf; diag scan (r23-verified verbatim); append kept (global
//     kb_g/kr_g + 512-slot LDS ring); publish kwmnk. Phase C: chunk T+1 vs
//     kept window [NK(T-2), NK(T)) from ring (<=256, workers cover [0,
//     NK(T-2))). Union = exactly all kept < chunk T+1:
//       worker c covers [0, NKg[c-3]); phase C at iter T (chunk c=T+1)
//       covers [knk_s[max(T-1,0)], knk_s[T+1]) = [NKg[c-3], NKg[c-1]). QED.
// All decision-critical FP math __f*_rn in exact ref op order (suppressor
// area first in union add, __fdiv_rn). absmax 0.0 r1-4,6-9,11-15,17-23.

#define M_TOT 8192
#define NMS_T 0.3f
#define RING  512

// ws layout (bytes)
#define WS_BOX   65536      // float4[8192] boxes_srt
#define WS_D     196608     // float[40960] d_srt
#define WS_VCNT  360448     // u32
#define WS_KWM   360512     // u64 kwmnk (zeroed by k2)
#define WS_STAT  360576     // u32[64] per-chunk status (zeroed by k2)
#define WS_KNKG  360832     // u32[64] NK after chunk T (gated by kwmnk)
#define WS_SFG   361472     // u64[128] worker flags, [2c+h] (gated by stat)
#define WS_MDIAG 393216     // ulonglong2[8192] in-chunk diag mask (128 KB)
#define WS_KBG   524288     // float4[8192] kept boxes (gated by kwmnk)
#define WS_KRG   655360     // u32[8192] kept sorted-rows

typedef unsigned long long u64t;

__device__ __forceinline__ uint32_t desc_key(float sv) {
    uint32_t u = __float_as_uint(sv);
    uint32_t m = (u & 0x80000000u) ? ~u : (u | 0x80000000u);
    return ~m;
}
__device__ __forceinline__ u64t rdl64(u64t v, int sl) {
    unsigned lo = (unsigned)__builtin_amdgcn_readlane((int)(unsigned)v, sl);
    unsigned hi = (unsigned)__builtin_amdgcn_readlane((int)(unsigned)(v >> 32), sl);
    return ((u64t)hi << 32) | lo;
}
__device__ __forceinline__ float area_of(float4 b) {
    return __fmul_rn(fmaxf(__fsub_rn(b.z, b.x), 0.0f),
                     fmaxf(__fsub_rn(b.w, b.y), 0.0f));
}

__device__ __forceinline__ void scatter_one(
    int i, int rank, u64t key,
    const float* __restrict__ det, const float* __restrict__ offsets,
    const float* __restrict__ scales,
    float4* __restrict__ boxes_srt, float* __restrict__ d_srt)
{
    uint32_t dkey = (uint32_t)(key >> 16);
    if (dkey >= 0x7FFFFFFFu) return;     // score <= 0: row stays zero
    int g = i >> 10;
    float d0 = __fadd_rn(offsets[g*5+0], __fmul_rn(det[i*5+0], scales[g*5+0]));
    float d1 = __fadd_rn(offsets[g*5+1], __fmul_rn(det[i*5+1], scales[g*5+1]));
    float d2 = __fadd_rn(offsets[g*5+2], __fmul_rn(det[i*5+2], scales[g*5+2]));
    float d3 = __fadd_rn(offsets[g*5+3], __fmul_rn(det[i*5+3], scales[g*5+3]));
    float d4 = __fadd_rn(offsets[g*5+4], __fmul_rn(det[i*5+4], scales[g*5+4]));
    d_srt[rank*5+0] = d0; d_srt[rank*5+1] = d1; d_srt[rank*5+2] = d2;
    d_srt[rank*5+3] = d3; d_srt[rank*5+4] = d4;
    float hw = __fmul_rn(d3, 0.5f), hh = __fmul_rn(d4, 0.5f);
    boxes_srt[rank] = make_float4(__fsub_rn(d1, hw), __fsub_rn(d2, hh),
                                  __fadd_rn(d1, hw), __fadd_rn(d2, hh));
}

// 128 blocks x 512 threads (r19/r23-proven)
__global__ __launch_bounds__(512) void k2_rank(
    const float* __restrict__ det, const float* __restrict__ offsets,
    const float* __restrict__ scales, const float* __restrict__ bounds,
    float4* __restrict__ boxes_srt, float* __restrict__ d_srt,
    unsigned int* __restrict__ vcnt, u64t* __restrict__ kwmnk,
    unsigned int* __restrict__ stat, float* __restrict__ out)
{
    __shared__ u64t skey[M_TOT];
    __shared__ float soff[40], sscl[40], sbnd[32];
    __shared__ int sTop;
    int t = threadIdx.x;
    int lane = t & 63;
    if (t == 0) sTop = 0;
    if (t < 40) { soff[t] = offsets[t]; sscl[t] = scales[t]; }
    if (t < 32) { sbnd[t] = bounds[t]; }
    if (blockIdx.x == 0 && t < 64) stat[t] = 0u;
    if (blockIdx.x == 0 && t == 0) *kwmnk = 0ull;
    __syncthreads();

    #pragma unroll 4
    for (int s = 0; s < 16; ++s) {
        int u = s * 512 + t;
        int g = u >> 10;
        float raw_s = det[u * 5 + 0];
        float cx    = det[u * 5 + 1];
        float cy    = det[u * 5 + 2];
        float score = __fadd_rn(soff[g * 5 + 0], __fmul_rn(raw_s, sscl[g * 5 + 0]));
        bool valid = (cx < sbnd[g*4+1]) && (cx > sbnd[g*4+0]) &&
                     (cy < sbnd[g*4+3]) && (cy > sbnd[g*4+2]);
        float sv = valid ? score : -1.0f;
        uint32_t dk = desc_key(sv);
        bool push = dk < 0x7FFFFFFFu;
        u64t key = ((u64t)dk << 16) | (unsigned)u;
        u64t bal = __ballot(push);
        if (bal) {
            int lw = 0;
            if (lane == 0) lw = atomicAdd(&sTop, __popcll(bal));
            int wbase = __builtin_amdgcn_readfirstlane(lw);
            if (push) {
                int off = __popcll(bal & ((1ull << lane) - 1ull));
                skey[wbase + off] = key;
            }
        }
    }
    __syncthreads();
    int V = sTop;
    int Vpad = (V + 15) & ~15;
    if (t < Vpad - V) skey[V + t] = ~0ull;
    {
        int zb = blockIdx.x * 320;       // 128 blocks x 320 = 40960
        for (int z = zb + t; z < zb + 320; z += 512) out[z] = 0.0f;
    }
    __syncthreads();
    if (t == 0) *vcnt = (unsigned)V;

    int grp = t >> 3;                    // 0..63
    int jq  = t & 7;
    int i = blockIdx.x * 64 + grp;       // 128*64 = 8192
    int g = i >> 10;
    float raw_s = det[i * 5 + 0];
    float cx    = det[i * 5 + 1];
    float cy    = det[i * 5 + 2];
    float score = __fadd_rn(soff[g * 5 + 0], __fmul_rn(raw_s, sscl[g * 5 + 0]));
    bool valid = (cx < sbnd[g*4+1]) && (cx > sbnd[g*4+0]) &&
                 (cy < sbnd[g*4+3]) && (cy > sbnd[g*4+2]);
    float sv = valid ? score : -1.0f;
    uint32_t dk = desc_key(sv);
    u64t ki = ((u64t)dk << 16) | (unsigned)i;
    const ulonglong2* skey2 = (const ulonglong2*)skey;
    int c = 0;
    int nit = Vpad >> 4;
    #pragma unroll 4
    for (int it = 0; it < nit; ++it) {
        ulonglong2 kj = skey2[it * 8 + jq];
        c += (kj.x < ki) + (kj.y < ki);
    }
    c += __shfl_xor(c, 1);
    c += __shfl_xor(c, 2);
    c += __shfl_xor(c, 4);
    if (jq == 0)
        scatter_one(i, c, ki, det, offsets, scales, boxes_srt, d_srt);
}

// ---- diag builders + incremental workers + on-fly consumer ----
// block 0: consumer; blocks 1..128: worker (c = (b-1)>>1, half = (b-1)&1)
__global__ __launch_bounds__(512) void k34_wrk(
    const float4* __restrict__ boxes_srt,
    const float* __restrict__ d_srt,
    const unsigned int* __restrict__ vcnt,
    ulonglong2* __restrict__ mdiag,
    u64t* __restrict__ kwmnk,
    unsigned int* __restrict__ stat,
    unsigned int* __restrict__ knk_g,
    u64t* __restrict__ sfg,
    float4* __restrict__ kb_g,
    unsigned int* __restrict__ kr_g,
    float* __restrict__ out)
{
    int V = (int)*vcnt;
    int nc = (V + 127) >> 7;
    int t = threadIdx.x;

    if (blockIdx.x != 0) {
        // ================= worker =================
        int wb = (int)blockIdx.x - 1;
        int c = wb >> 1, h = wb & 1;
        if (c >= nc) return;
        __shared__ float4 cbw[128];
        __shared__ float  caw[128];
        __shared__ u64t   sOr;
        if (t == 0) sOr = 0ull;
        if (t < 128) {
            float4 b = boxes_srt[min(c * 128 + t, M_TOT - 1)];
            cbw[t] = b; caw[t] = area_of(b);
        }
        __syncthreads();
        // diag: my 64 rows x 128 cols (256 threads: row x 4 col-words)
        if (t < 256) {
            int rl = h * 64 + (t & 63);
            int q = (t >> 6) & 3;
            float4 bi = cbw[rl];
            float  ai = caw[rl];
            unsigned bits = 0u;
            int j0 = 32 * q;
            #pragma unroll 8
            for (int b = 0; b < 32; ++b) {
                int jl = j0 + b;
                float4 bj = cbw[jl];
                float  aj = caw[jl];
                float iw = fmaxf(__fsub_rn(fminf(bi.z, bj.z), fmaxf(bi.x, bj.x)), 0.0f);
                float ih = fmaxf(__fsub_rn(fminf(bi.w, bj.w), fmaxf(bi.y, bj.y)), 0.0f);
                float inter = __fmul_rn(iw, ih);
                float uni   = __fsub_rn(__fadd_rn(ai, aj), inter);
                float iou   = __fdiv_rn(inter, fmaxf(uni, 1e-9f));
                if (jl > rl && iou > NMS_T) bits |= 1u << b;
            }
            ((unsigned*)mdiag)[(c * 128 + rl) * 4 + q] = bits;
        }
        __syncthreads();                 // mdiag writes complete (vmcnt drained)
        if (t == 0) {
            __threadfence();
            __hip_atomic_fetch_add(&stat[c], 1u,
                                   __ATOMIC_RELEASE, __HIP_MEMORY_SCOPE_AGENT);
        }
        // incremental suppression vs kept through chunk c-3
        int boxl = t & 63, slice = t >> 6;
        float4 bme = cbw[h * 64 + boxl];
        float  ame = caw[h * 64 + boxl];
        bool suppd = false;
        int Tcap = c - 3;
        if (Tcap >= 0) {
            unsigned prevNK = 0;
            while (true) {
                u64t kw = __hip_atomic_load(kwmnk, __ATOMIC_RELAXED,
                                            __HIP_MEMORY_SCOPE_AGENT);
                unsigned P  = (unsigned)kw;
                unsigned NK = (unsigned)(kw >> 32);
                bool last = (int)P >= Tcap + 1;
                unsigned cap;
                if (last) {
                    (void)__hip_atomic_load(kwmnk, __ATOMIC_ACQUIRE,
                                            __HIP_MEMORY_SCOPE_AGENT);
                    cap = knk_g[Tcap];
                } else if (NK > prevNK) {
                    (void)__hip_atomic_load(kwmnk, __ATOMIC_ACQUIRE,
                                            __HIP_MEMORY_SCOPE_AGENT);
                    cap = NK;
                } else {
                    __builtin_amdgcn_s_sleep(2);
                    continue;
                }
                for (unsigned j = prevNK + (unsigned)slice; j < cap; j += 8) {
                    float4 bj = kb_g[j];
                    float  aj = area_of(bj);
                    float iw = fmaxf(__fsub_rn(fminf(bj.z, bme.z), fmaxf(bj.x, bme.x)), 0.0f);
                    float ih = fmaxf(__fsub_rn(fminf(bj.w, bme.w), fmaxf(bj.y, bme.y)), 0.0f);
                    float inter = __fmul_rn(iw, ih);
                    float uni   = __fsub_rn(__fadd_rn(aj, ame), inter);
                    float iou   = __fdiv_rn(inter, fmaxf(uni, 1e-9f));
                    if (iou > NMS_T) suppd = true;
                }
                prevNK = cap;
                if (last) break;
            }
        }
        u64t wm = __ballot(suppd);       // lane = box, per-wave slice OR
        if ((t & 63) == 0) atomicOr(&sOr, wm);
        __syncthreads();
        if (t == 0) {
            sfg[2 * c + h] = sOr;
            __threadfence();
            __hip_atomic_fetch_add(&stat[c], 4u,
                                   __ATOMIC_RELEASE, __HIP_MEMORY_SCOPE_AGENT);
        }
        return;
    }

    // ================= consumer =================
    __shared__ float4 kbR[RING];
    __shared__ float  kaR[RING];
    __shared__ float4 cb[128];
    __shared__ float  ca[128];
    __shared__ unsigned sf[2][128];
    __shared__ int knk_s[65];
    __shared__ int s_nk;
    int lane = t & 63, wv = t >> 6;
    if (t == 0) { s_nk = 0; knk_s[0] = 0; }
    if (t < 256) sf[t >> 7][t & 127] = 0u;
    if (t < 128) {
        float4 b = boxes_srt[t];
        cb[t] = b; ca[t] = area_of(b);
    }
    __syncthreads();
    if (nc <= 0) return;

    u64t wf_lo = 0, wf_hi = 0;
    ulonglong2 bl, bh;
    if (wv == 0) {
        while (__hip_atomic_load(&stat[0], __ATOMIC_RELAXED,
                                 __HIP_MEMORY_SCOPE_AGENT) != 10u)
            __builtin_amdgcn_s_sleep(2);
        (void)__hip_atomic_load(&stat[0], __ATOMIC_ACQUIRE,
                                __HIP_MEMORY_SCOPE_AGENT);
        bl = mdiag[lane];
        bh = mdiag[64 + lane];
        wf_lo = sfg[0]; wf_hi = sfg[1];  // zero (worker 0 has no coverage)
    }

    for (int T = 0; T < nc; ++T) {
        if (wv == 0) {
            // ---- prefetch chunk T+1: one merged poll ----
            ulonglong2 nbl, nbh; u64t nwlo = 0, nwhi = 0;
            bool hn = (T + 1 < nc);
            if (hn) {
                int c = T + 1;
                while (__hip_atomic_load(&stat[c], __ATOMIC_RELAXED,
                                         __HIP_MEMORY_SCOPE_AGENT) != 10u)
                    __builtin_amdgcn_s_sleep(2);
                (void)__hip_atomic_load(&stat[c], __ATOMIC_ACQUIRE,
                                        __HIP_MEMORY_SCOPE_AGENT);
                nbl = mdiag[c * 128 + lane];
                nbh = mdiag[c * 128 + 64 + lane];
                nwlo = sfg[2 * c]; nwhi = sfg[2 * c + 1];
            }
            // ---- dead flags: worker | residual ----
            unsigned flo = sf[T & 1][lane];
            unsigned fhi = sf[T & 1][64 + lane];
            u64t live_lo = ~(wf_lo | __ballot(flo != 0u));
            u64t live_hi = ~(wf_hi | __ballot(fhi != 0u));
            int rem = V - T * 128;
            if (rem < 128) {
                live_lo &= (rem >= 64) ? ~0ull : ((rem <= 0) ? 0ull : ((1ull << rem) - 1ull));
                int rh2 = rem - 64;
                live_hi &= (rh2 >= 64) ? ~0ull : ((rh2 <= 0) ? 0ull : ((1ull << rh2) - 1ull));
            }
            // ---- in-chunk serial resolve (r23-verified) ----
            u64t km_lo = 0, km_hi = 0;
            while (live_lo) {
                int bs = (int)__builtin_ctzll(live_lo);
                km_lo |= 1ull << bs;
                u64t rml = rdl64(bl.x, bs);
                u64t rmh = rdl64(bl.y, bs);
                live_lo &= ~rml & ~(1ull << bs);
                live_hi &= ~rmh;
            }
            while (live_hi) {
                int bs = (int)__builtin_ctzll(live_hi);
                km_hi |= 1ull << bs;
                u64t rmh = rdl64(bh.y, bs);   // bh.x irrelevant: live_lo==0
                live_hi &= ~rmh & ~(1ull << bs);
            }
            // ---- append kept ----
            int pl = __popcll(km_lo);
            int nkm = pl + __popcll(km_hi);
            int snk = s_nk;
            for (int p = 0; p < 2; ++p) {
                int idx = lane + 64 * p;
                if (idx < nkm) {
                    int rl2;
                    if (idx < pl) {
                        u64t x = km_lo;
                        for (int k = 0; k < idx; ++k) x &= x - 1;
                        rl2 = (int)__builtin_ctzll(x);
                    } else {
                        u64t x = km_hi;
                        int ii = idx - pl;
                        for (int k = 0; k < ii; ++k) x &= x - 1;
                        rl2 = 64 + (int)__builtin_ctzll(x);
                    }
                    int r = T * 128 + rl2;
                    float4 b = cb[rl2];
                    float  a = ca[rl2];
                    int o = snk + idx;
                    kb_g[o] = b;
                    kr_g[o] = (unsigned)r;
                    kbR[o & (RING - 1)] = b;
                    kaR[o & (RING - 1)] = a;
                }
            }
            asm volatile("s_waitcnt vmcnt(0)" ::: "memory");  // kb_g/kr_g done
            if (t == 0) {
                knk_g[T] = (unsigned)(snk + nkm);
                __threadfence();
                __hip_atomic_store(kwmnk,
                                   ((u64t)(unsigned)(snk + nkm) << 32) | (unsigned)(T + 1),
                                   __ATOMIC_RELEASE, __HIP_MEMORY_SCOPE_AGENT);
                s_nk = snk + nkm;
                knk_s[T + 1] = snk + nkm;
            }
            wf_lo = nwlo; wf_hi = nwhi;
            if (hn) { bl = nbl; bh = nbh; }
        } else if (t >= 64 && t < 192) {
            sf[(T + 1) & 1][t - 64] = 0u;  // zero next parity (disjoint)
        }
        __syncthreads();
        // ---- phase C: chunk T+1 vs recent-kept window (ring) ----
        if (T + 1 < nc) {
            int rl = t & 127, q = t >> 7;
            float4 br = boxes_srt[min((T + 1) * 128 + rl, M_TOT - 1)];
            float  ar = area_of(br);
            if (q == 0) { cb[rl] = br; ca[rl] = ar; }
            int jb0 = knk_s[(T - 1) > 0 ? (T - 1) : 0];
            int je0 = knk_s[T + 1];
            int n = je0 - jb0;
            int per = (n + 3) >> 2;
            int jb = jb0 + q * per;
            int je = jb + per; if (je > je0) je = je0;
            bool supp = false;
            for (int j = jb; j < je; ++j) {
                float4 bj = kbR[j & (RING - 1)];
                float  aj = kaR[j & (RING - 1)];
                float iw = fmaxf(__fsub_rn(fminf(bj.z, br.z), fmaxf(bj.x, br.x)), 0.0f);
                float ih = fmaxf(__fsub_rn(fminf(bj.w, br.w), fmaxf(bj.y, br.y)), 0.0f);
                float inter = __fmul_rn(iw, ih);
                float uni   = __fsub_rn(__fadd_rn(aj, ar), inter);
                float iou   = __fdiv_rn(inter, fmaxf(uni, 1e-9f));
                supp = supp || (iou > NMS_T);
            }
            if (supp)
                ((volatile unsigned char*)&sf[(T + 1) & 1][rl])[q] = 1;
        }
        __syncthreads();
    }

    // ---- final: write kept output rows ----
    {
        int nk = s_nk;
        for (int idx = t; idx < nk; idx += 512) {
            int r = (int)kr_g[idx];
            out[r * 5 + 0] = d_srt[r * 5 + 0];
            out[r * 5 + 1] = d_srt[r * 5 + 1];
            out[r * 5 + 2] = d_srt[r * 5 + 2];
            out[r * 5 + 3] = d_srt[r * 5 + 3];
            out[r * 5 + 4] = d_srt[r * 5 + 4];
        }
    }
}

extern "C" void kernel_launch(void* const* d_in, const int* in_sizes, int n_in,
                              void* d_out, int out_size, void* d_ws, size_t ws_size,
                              hipStream_t stream) {
    const float* det     = (const float*)d_in[0];
    const float* offsets = (const float*)d_in[1];
    const float* scales  = (const float*)d_in[2];
    const float* bounds  = (const float*)d_in[3];
    float* out = (float*)d_out;
    char* ws = (char*)d_ws;
    float4*       boxes = (float4*)(ws + WS_BOX);
    float*        d_srt = (float*)(ws + WS_D);
    unsigned int* vcnt  = (unsigned int*)(ws + WS_VCNT);
    u64t*         kwmnk = (u64t*)(ws + WS_KWM);
    unsigned int* stat  = (unsigned int*)(ws + WS_STAT);
    unsigned int* knkg  = (unsigned int*)(ws + WS_KNKG);
    u64t*         sfg   = (u64t*)(ws + WS_SFG);
    ulonglong2*   mdiag = (ulonglong2*)(ws + WS_MDIAG);
    float4*       kb_g  = (float4*)(ws + WS_KBG);
    unsigned int* kr_g  = (unsigned int*)(ws + WS_KRG);

    k2_rank<<<128, 512, 0, stream>>>(det, offsets, scales, bounds, boxes, d_srt,
                                     vcnt, kwmnk, stat, out);
    k34_wrk<<<129, 512, 0, stream>>>(boxes, d_srt, vcnt, mdiag, kwmnk, stat,
                                     knkg, sfg, kb_g, kr_g, out);
}